// Round 15
// baseline (304.698 us; speedup 1.0000x reference)
//
#include <hip/hip_runtime.h>
#include <hip/hip_bf16.h>

#define NHEAD 8
#define IMG   3136      // 56*56
#define MTOT  100352    // 32*3136

typedef __attribute__((ext_vector_type(2))) _Float16 f16x2;
typedef __attribute__((ext_vector_type(4))) float    f32x4;
typedef __attribute__((ext_vector_type(16))) float   f32x16;
typedef __attribute__((ext_vector_type(8))) short    bf16x8;
typedef __attribute__((ext_vector_type(2))) int      i32x2;
typedef __attribute__((ext_vector_type(4))) int      i32x4;

// swizzle for 512B rows: row bits 0-2 -> byte bits 4-6, row bit 3 -> byte bit 7 (bijective)
#define SWZA(byteoff, r) ((byteoff) ^ (((r)&7)<<4) ^ ((((r)>>3)&1)<<7))

__device__ __forceinline__ short f2bf(float f){
  union { float fv; unsigned u; } a; a.fv = f;
  unsigned u = a.u;
  unsigned r = (u + 0x7fffu + ((u >> 16) & 1u)) >> 16;
  return (short)r;
}

// hardware packed f32->bf16 (RNE), 1 instruction for 2 values
__device__ __forceinline__ unsigned cvtpk(float lo, float hi){
  unsigned r;
  asm("v_cvt_pk_bf16_f32 %0, %1, %2" : "=v"(r) : "v"(lo), "v"(hi));
  return r;
}

// sigmoid-form GeLU: v*sigmoid(1.702v). Verified within threshold (R9-R14 absmax 0.03125).
__device__ __forceinline__ float gelu_s(float v){
  float e = __expf(-1.702f*v);
  return v*__builtin_amdgcn_rcpf(1.f + e);
}

// ---------------- K0: weight prep ----------------
// blocks 0..127  : w1p fragment-packed  (fc1_w [256][1024] -> [(f*16+kk)*64+lane][8] bf16)
// blocks 128..255: w2p fragment-packed  (fc2_w [1024][256] -> [(f*64+kk)*64+lane][8] bf16)
// block 256      : spatial W -> MFMA A-frag pack wspA[h][mt][kt][lane][8] bf16 (i,j zero-padded)
__global__ void prep_k(const float* __restrict__ fc1w, const float* __restrict__ fc2w,
                       const float* __restrict__ spw,
                       short* __restrict__ w1p, short* __restrict__ w2p,
                       short* __restrict__ wspA)
{
  int bid = blockIdx.x, t = threadIdx.x;
  if (bid < 128) {
    int id = bid*256 + t;            // [0, 32768)
    int l = id & 63, fk = id >> 6;   // fk = f*16+kk
    int kk = fk & 15, f = fk >> 4;
    int n = f*32 + (l & 31);
    int kbase = kk*16 + (l >> 5)*8;
    bf16x8 o;
    #pragma unroll
    for (int e = 0; e < 8; ++e) o[e] = f2bf(fc1w[(size_t)(kbase+e)*1024 + n]);
    *(bf16x8*)(w1p + (size_t)id*8) = o;
  } else if (bid < 256) {
    int id = (bid-128)*256 + t;      // [0, 32768)
    int l = id & 63, fk = id >> 6;   // fk = f*64+kk
    int kk = fk & 63, f = fk >> 6;
    int n = f*32 + (l & 31);
    int kbase = kk*16 + (l >> 5)*8;
    bf16x8 o;
    #pragma unroll
    for (int e = 0; e < 8; ++e) o[e] = f2bf(fc2w[(size_t)(kbase+e)*256 + n]);
    *(bf16x8*)(w2p + (size_t)id*8) = o;
  } else {
    // 4096 fragment-chunks: idx = ((h*2+mt)*4+kt)*64 + lane
    #pragma unroll
    for (int k = 0; k < 16; ++k) {
      int idx = t + k*256;
      int lane = idx & 63;
      int kt = (idx >> 6) & 3;
      int mt = (idx >> 8) & 1;
      int h  = idx >> 9;
      int i  = mt*32 + (lane & 31);
      int jb = kt*16 + (lane >> 5)*8;
      bf16x8 o;
      #pragma unroll
      for (int e = 0; e < 8; ++e) {
        int j = jb + e;
        float v = (i < 49 && j < 49) ? spw[(size_t)(h*49 + i)*49 + j] : 0.f;
        o[e] = f2bf(v);
      }
      *(bf16x8*)(wspA + (size_t)idx*8) = o;
    }
  }
}

// ---------------- K1: LN1 + spatial window MLP (MFMA) + residual -> x1 (=d_out) ----------------
// 1296 blocks x 512 thr; 2 windows/block; wave = head. LDS: lxT 64 KB + murs ~0.9 KB -> 2 blk/CU.
__global__ __launch_bounds__(512,4) void win_k(
    const float* __restrict__ x, const float* __restrict__ n1w, const float* __restrict__ n1b,
    const float* __restrict__ spb, const short* __restrict__ wspA,
    float* __restrict__ x1)
{
  extern __shared__ char wsm[];
  char*  lxT  = wsm;                      // 65536
  float* murs = (float*)(wsm + 65536);    // [2][56][2]
  int t = threadIdx.x, lane = t & 63, wave = t >> 6;
  int bid = blockIdx.x;

  // ---- LN stats: batched loads (one latency exposure), then independent reduces ----
  {
    f32x4 xv[2][7];
    #pragma unroll
    for (int w = 0; w < 2; ++w) {
      int win = bid*2 + w;
      int b = win/81, rem = win - b*81, wi = rem/9, wj = rem - (rem/9)*9;
      #pragma unroll
      for (int j = 0; j < 7; ++j) {
        int i = wave + 8*j;
        int iy = i/7, ix = i - iy*7;
        int hh = wi*7 + iy - 4, ww = wj*7 + ix - 4;
        bool valid = (i < 49) && hh >= 0 && hh < 56 && ww >= 0 && ww < 56;  // wave-uniform
        if (valid)
          xv[w][j] = *(const f32x4*)(x + ((size_t)(b*IMG + hh*56 + ww))*256 + lane*4);
      }
    }
    #pragma unroll
    for (int w = 0; w < 2; ++w) {
      int win = bid*2 + w;
      int b = win/81, rem = win - b*81, wi = rem/9, wj = rem - (rem/9)*9;
      #pragma unroll
      for (int j = 0; j < 7; ++j) {
        int i = wave + 8*j;
        int iy = i/7, ix = i - iy*7;
        int hh = wi*7 + iy - 4, ww = wj*7 + ix - 4;
        bool valid = (i < 49) && hh >= 0 && hh < 56 && ww >= 0 && ww < 56;  // wave-uniform
        if (!valid) continue;
        f32x4 v = xv[w][j];
        float s  = v[0]+v[1]+v[2]+v[3];
        float s2 = v[0]*v[0]+v[1]*v[1]+v[2]*v[2]+v[3]*v[3];
        #pragma unroll
        for (int m = 1; m < 64; m <<= 1) { s += __shfl_xor(s, m); s2 += __shfl_xor(s2, m); }
        float mu = s * (1.f/256.f);
        float rs = rsqrtf(s2*(1.f/256.f) - mu*mu + 1e-5f);
        if (lane == 0) { murs[(w*56+i)*2] = mu; murs[(w*56+i)*2+1] = rs; }
      }
    }
  }
  __syncthreads();

  // ---- pass2: thread = (win, c); column-read x, LN-apply, write x^T bf16 into lxT ----
  {
    int w = t >> 8, c = t & 255;
    int win = bid*2 + w;
    int b = win/81, rem = win - b*81, wi = rem/9, wj = rem - (rem/9)*9;
    float nwc = n1w[c], nbc = n1b[c];
    char* rowb = lxT + c*256;
    #pragma unroll
    for (int cj = 0; cj < 7; ++cj) {
      float vals[8];
      #pragma unroll
      for (int e = 0; e < 8; ++e) {
        int p = cj*8 + e;                 // compile-time
        float fv = 0.f;
        if (p < 49) {
          int iy = p/7, ix = p - iy*7;    // compile-time
          int hh = wi*7 + iy - 4, ww = wj*7 + ix - 4;
          if (hh >= 0 && hh < 56 && ww >= 0 && ww < 56) {   // wave-uniform
            float mu = murs[(w*56+p)*2], rs = murs[(w*56+p)*2+1];
            float xv = x[((size_t)(b*IMG + hh*56 + ww))*256 + c];
            fv = (xv - mu)*rs*nwc + nbc;
          }
        }
        vals[e] = fv;
      }
      i32x4 pk;
      pk[0] = cvtpk(vals[0], vals[1]); pk[1] = cvtpk(vals[2], vals[3]);
      pk[2] = cvtpk(vals[4], vals[5]); pk[3] = cvtpk(vals[6], vals[7]);
      *(i32x4*)(rowb + SWZA(w*128 + cj*16, c)) = pk;
    }
    i32x4 z = {0,0,0,0};
    *(i32x4*)(rowb + SWZA(w*128 + 112, c)) = z;   // j 56..63 pad
  }
  __syncthreads();

  // ---- MFMA dot: wave = head; 2 windows; i-tiles mt=0,1; K=49(pad 64) over 4 kt ----
  int h = wave, d = lane & 31, lk = lane >> 5;
  const short* wA = wspA + h*4096;
  int c = h*32 + d;
  f32x16 a00, a01, a10, a11;   // [mt][win]
  #pragma unroll
  for (int q = 0; q < 16; ++q) { a00[q]=0.f; a01[q]=0.f; a10[q]=0.f; a11[q]=0.f; }
  #pragma unroll
  for (int kt = 0; kt < 4; ++kt) {
    bf16x8 A0 = *(const bf16x8*)(wA + (kt*64 + lane)*8);
    bf16x8 A1 = *(const bf16x8*)(wA + ((4+kt)*64 + lane)*8);
    int bo = kt*32 + lk*16;
    bf16x8 B0 = *(const bf16x8*)(lxT + c*256 + SWZA(bo, c));
    bf16x8 B1 = *(const bf16x8*)(lxT + c*256 + SWZA(128 + bo, c));
    a00 = __builtin_amdgcn_mfma_f32_32x32x16_bf16(A0, B0, a00, 0,0,0);
    a10 = __builtin_amdgcn_mfma_f32_32x32x16_bf16(A1, B0, a10, 0,0,0);
    a01 = __builtin_amdgcn_mfma_f32_32x32x16_bf16(A0, B1, a01, 0,0,0);
    a11 = __builtin_amdgcn_mfma_f32_32x32x16_bf16(A1, B1, a11, 0,0,0);
  }

  // ---- epilogue: x1 = x + spatial + bias ----
  #pragma unroll
  for (int w = 0; w < 2; ++w) {
    int win = bid*2 + w;
    int b = win/81, rem = win - b*81, wi = rem/9, wj = rem - (rem/9)*9;
    #pragma unroll
    for (int mt = 0; mt < 2; ++mt) {
      #pragma unroll
      for (int r = 0; r < 16; ++r) {
        int i = mt*32 + (r&3) + 8*(r>>2) + 4*lk;
        if (i < 49) {
          int iy = i/7, ix = i - iy*7;
          int hh = wi*7 + iy - 4, ww = wj*7 + ix - 4;
          if (hh >= 0 && hh < 56 && ww >= 0 && ww < 56) {
            size_t off = ((size_t)(b*IMG + hh*56 + ww))*256 + c;
            float av = mt==0 ? (w==0 ? a00[r] : a01[r]) : (w==0 ? a10[r] : a11[r]);
            x1[off] = x[off] + av + spb[h*49 + i];
          }
        }
      }
    }
  }
}

// ---------------- K2: fused LN2 + fc1 + GeLU + fc2 + residual (in-place on d_out) ----------------
// 1568 blocks x 512 thr (8 waves). 64-row tile. LDS: a2[64][512B] + hc[64][512B] = 64 KB
// -> 2 blocks/CU. R13 champion structure; change: bq prologues hoisted into the dead slots
// (GEMM2's above GeLU; next chunk's GEMM1 above the trailing barrier). Zero extra registers.
__global__ __launch_bounds__(512,4) void mlp_k(
    const float* __restrict__ x1, float* __restrict__ out,
    const short* __restrict__ w1p, const short* __restrict__ w2p,
    const float* __restrict__ n2w, const float* __restrict__ n2b,
    const float* __restrict__ b1, const float* __restrict__ b2)
{
  extern __shared__ char sm[];
  char* a2  = sm;                 // 32768
  char* hcb = sm + 32768;         // 32768

  int t = threadIdx.x, lane = t & 63, wave = t >> 6;
  int m0 = blockIdx.x * 64;
  int lr = lane & 31, lk = lane >> 5;
  int wn = wave;                      // 8 col-slices of 32

  // rolling weight bases (shorts); chunk ch stride: g1 += 65536, g2 += 8192
  const short* g1 = w1p + ((size_t)(wn*16)*64 + lane)*8;
  const short* g2 = w2p + ((size_t)(wn*64)*64 + lane)*8;

  // ch=0 GEMM1 prologue issued before LN (rides over it)
  bf16x8 bq[4];
  #pragma unroll
  for (int k = 0; k < 4; ++k) bq[k] = *(const bf16x8*)(g1 + (size_t)k*512);

  // ---- Phase A: LN2 of 64 rows -> a2 (bf16, swizzled) ----
  {
    f32x4 nw = *(const f32x4*)(n2w + lane*4);
    f32x4 nb = *(const f32x4*)(n2b + lane*4);
    #pragma unroll
    for (int rq = 0; rq < 8; ++rq) {
      int rr = wave*8 + rq;
      f32x4 v = *(const f32x4*)(x1 + (size_t)(m0+rr)*256 + lane*4);
      float s  = v[0]+v[1]+v[2]+v[3];
      float s2 = v[0]*v[0]+v[1]*v[1]+v[2]*v[2]+v[3]*v[3];
      #pragma unroll
      for (int m = 1; m < 64; m <<= 1){ s += __shfl_xor(s,m); s2 += __shfl_xor(s2,m); }
      float mu = s*(1.f/256.f);
      float rs = rsqrtf(s2*(1.f/256.f) - mu*mu + 1e-5f);
      float y0 = (v[0]-mu)*rs*nw[0] + nb[0];
      float y1 = (v[1]-mu)*rs*nw[1] + nb[1];
      float y2 = (v[2]-mu)*rs*nw[2] + nb[2];
      float y3 = (v[3]-mu)*rs*nw[3] + nb[3];
      i32x2 pk; pk[0] = cvtpk(y0,y1); pk[1] = cvtpk(y2,y3);
      *(i32x2*)(a2 + SWZA(lane*8, rr) + rr*512) = pk;
    }
  }
  __syncthreads();

  f32x16 accO[2];
  #pragma unroll
  for (int i=0;i<2;++i)
    #pragma unroll
    for (int q=0;q<16;++q) accO[i][q] = 0.f;

  for (int ch = 0; ch < 4; ++ch) {      // rolled
    f32x16 accH[2];
    #pragma unroll
    for (int i=0;i<2;++i)
      #pragma unroll
      for (int q=0;q<16;++q) accH[i][q] = 0.f;

    // ---- GEMM1: accH[64m][32n] = a2[64][256] @ W1-chunk (bq preloaded last phase) ----
    __builtin_amdgcn_s_setprio(1);
    #pragma unroll
    for (int kk = 0; kk < 16; ++kk) {
      bf16x8 b = bq[kk & 3];
      if (kk < 12) bq[kk & 3] = *(const bf16x8*)(g1 + (size_t)(kk+4)*512);
      int kb = kk*32 + lk*16;
      bf16x8 a0 = *(const bf16x8*)(a2 + SWZA(kb, lr) + lr*512);
      bf16x8 a1 = *(const bf16x8*)(a2 + SWZA(kb, 32+lr) + (32+lr)*512);
      accH[0] = __builtin_amdgcn_mfma_f32_32x32x16_bf16(a0, b, accH[0], 0,0,0);
      accH[1] = __builtin_amdgcn_mfma_f32_32x32x16_bf16(a1, b, accH[1], 0,0,0);
    }
    __builtin_amdgcn_s_setprio(0);

    // GEMM2 prologue hoisted above GeLU (bq dead here; rides over GeLU VALU + barrier)
    #pragma unroll
    for (int k = 0; k < 4; ++k) bq[k] = *(const bf16x8*)(g2 + (size_t)k*512);

    // ---- bias + GeLU -> hc (bf16, swizzled); paired cvt_pk ----
    {
      float b1v = b1[ch*256 + wn*32 + lr];
      int colb = (wn*32 + lr)*2;
      #pragma unroll
      for (int ms = 0; ms < 2; ++ms) {
        #pragma unroll
        for (int r2 = 0; r2 < 8; ++r2) {
          int r = r2*2;
          float g0 = gelu_s(accH[ms][r]   + b1v);
          float g1v = gelu_s(accH[ms][r+1] + b1v);
          unsigned pw = cvtpk(g0, g1v);
          int row0 = ms*32 + (r&3) + 8*(r>>2) + 4*lk;   // r even
          int row1 = row0 + 1;
          *(short*)(hcb + SWZA(colb, row0) + row0*512) = (short)(pw & 0xffffu);
          *(short*)(hcb + SWZA(colb, row1) + row1*512) = (short)(pw >> 16);
        }
      }
    }
    __syncthreads();

    // ---- GEMM2: accO[64m][32n] += hc[64][256] @ W2-chunk ----
    __builtin_amdgcn_s_setprio(1);
    #pragma unroll
    for (int kk = 0; kk < 16; ++kk) {
      bf16x8 b = bq[kk & 3];
      if (kk < 12) bq[kk & 3] = *(const bf16x8*)(g2 + (size_t)(kk+4)*512);
      int kb = kk*32 + lk*16;
      bf16x8 a0 = *(const bf16x8*)(hcb + SWZA(kb, lr) + lr*512);
      bf16x8 a1 = *(const bf16x8*)(hcb + SWZA(kb, 32+lr) + (32+lr)*512);
      accO[0] = __builtin_amdgcn_mfma_f32_32x32x16_bf16(a0, b, accO[0], 0,0,0);
      accO[1] = __builtin_amdgcn_mfma_f32_32x32x16_bf16(a1, b, accO[1], 0,0,0);
    }
    __builtin_amdgcn_s_setprio(0);

    // advance bases; next GEMM1 prologue hoisted above the trailing barrier
    g1 += 65536;
    g2 += 8192;
    if (ch < 3) {
      #pragma unroll
      for (int k = 0; k < 4; ++k) bq[k] = *(const bf16x8*)(g1 + (size_t)k*512);
      __syncthreads();   // protect hc before next chunk's GeLU (dead on last chunk)
    }
  }

  // ---- epilogue: out = x1 + accO + b2 ----
  {
    int col = wn*32 + lr;
    float b2v = b2[col];
    #pragma unroll
    for (int ms = 0; ms < 2; ++ms) {
      #pragma unroll
      for (int r = 0; r < 16; ++r) {
        int row = ms*32 + (r&3) + 8*(r>>2) + 4*lk;
        size_t off = (size_t)(m0 + row)*256 + col;
        out[off] = x1[off] + accO[ms][r] + b2v;
      }
    }
  }
}

extern "C" void kernel_launch(void* const* d_in, const int* in_sizes, int n_in,
                              void* d_out, int out_size, void* d_ws, size_t ws_size,
                              hipStream_t stream) {
  const float* x    = (const float*)d_in[0];
  const float* n1w  = (const float*)d_in[1];
  const float* n1b  = (const float*)d_in[2];
  const float* spw  = (const float*)d_in[3];
  const float* spb  = (const float*)d_in[4];
  const float* n2w  = (const float*)d_in[5];
  const float* n2b  = (const float*)d_in[6];
  const float* fc1w = (const float*)d_in[7];
  const float* fc1b = (const float*)d_in[8];
  const float* fc2w = (const float*)d_in[9];
  const float* fc2b = (const float*)d_in[10];
  float* outp = (float*)d_out;

  char* ws = (char*)d_ws;
  short* w1p  = (short*)ws;                   // 524288 B
  short* w2p  = (short*)(ws + 524288);        // 524288 B
  short* wspA = (short*)(ws + 1048576);       // 65536 B

  prep_k<<<257, 256, 0, stream>>>(fc1w, fc2w, spw, w1p, w2p, wspA);

  hipFuncSetAttribute(reinterpret_cast<const void*>(win_k),
                      hipFuncAttributeMaxDynamicSharedMemorySize, 66432);
  win_k<<<1296, 512, 66432, stream>>>(x, n1w, n1b, spb, wspA, outp);

  hipFuncSetAttribute(reinterpret_cast<const void*>(mlp_k),
                      hipFuncAttributeMaxDynamicSharedMemorySize, 65536);
  mlp_k<<<MTOT/64, 512, 65536, stream>>>(outp, outp, w1p, w2p, n2w, n2b, fc1b, fc2b);
}

// Round 16
// 289.392 us; speedup vs baseline: 1.0529x; 1.0529x over previous
//
#include <hip/hip_runtime.h>
#include <hip/hip_bf16.h>

#define NHEAD 8
#define IMG   3136      // 56*56
#define MTOT  100352    // 32*3136

typedef __attribute__((ext_vector_type(2))) _Float16 f16x2;
typedef __attribute__((ext_vector_type(4))) float    f32x4;
typedef __attribute__((ext_vector_type(16))) float   f32x16;
typedef __attribute__((ext_vector_type(8))) short    bf16x8;
typedef __attribute__((ext_vector_type(2))) int      i32x2;
typedef __attribute__((ext_vector_type(4))) int      i32x4;

// swizzle for 512B rows: row bits 0-2 -> byte bits 4-6, row bit 3 -> byte bit 7 (bijective)
#define SWZA(byteoff, r) ((byteoff) ^ (((r)&7)<<4) ^ ((((r)>>3)&1)<<7))

__device__ __forceinline__ short f2bf(float f){
  union { float fv; unsigned u; } a; a.fv = f;
  unsigned u = a.u;
  unsigned r = (u + 0x7fffu + ((u >> 16) & 1u)) >> 16;
  return (short)r;
}

// hardware packed f32->bf16 (RNE), 1 instruction for 2 values
__device__ __forceinline__ unsigned cvtpk(float lo, float hi){
  unsigned r;
  asm("v_cvt_pk_bf16_f32 %0, %1, %2" : "=v"(r) : "v"(lo), "v"(hi));
  return r;
}

// sigmoid-form GeLU: v*sigmoid(1.702v). Verified within threshold (R9-R15 absmax 0.03125).
__device__ __forceinline__ float gelu_s(float v){
  float e = __expf(-1.702f*v);
  return v*__builtin_amdgcn_rcpf(1.f + e);
}

// ---------------- K0: weight prep ----------------
// blocks 0..127  : w1p fragment-packed  (fc1_w [256][1024] -> [(f*16+kk)*64+lane][8] bf16)
// blocks 128..255: w2p fragment-packed  (fc2_w [1024][256] -> [(f*64+kk)*64+lane][8] bf16)
// block 256      : spatial W -> MFMA A-frag pack wspA[h][mt][kt][lane][8] bf16 (i,j zero-padded)
__global__ void prep_k(const float* __restrict__ fc1w, const float* __restrict__ fc2w,
                       const float* __restrict__ spw,
                       short* __restrict__ w1p, short* __restrict__ w2p,
                       short* __restrict__ wspA)
{
  int bid = blockIdx.x, t = threadIdx.x;
  if (bid < 128) {
    int id = bid*256 + t;            // [0, 32768)
    int l = id & 63, fk = id >> 6;   // fk = f*16+kk
    int kk = fk & 15, f = fk >> 4;
    int n = f*32 + (l & 31);
    int kbase = kk*16 + (l >> 5)*8;
    bf16x8 o;
    #pragma unroll
    for (int e = 0; e < 8; ++e) o[e] = f2bf(fc1w[(size_t)(kbase+e)*1024 + n]);
    *(bf16x8*)(w1p + (size_t)id*8) = o;
  } else if (bid < 256) {
    int id = (bid-128)*256 + t;      // [0, 32768)
    int l = id & 63, fk = id >> 6;   // fk = f*64+kk
    int kk = fk & 63, f = fk >> 6;
    int n = f*32 + (l & 31);
    int kbase = kk*16 + (l >> 5)*8;
    bf16x8 o;
    #pragma unroll
    for (int e = 0; e < 8; ++e) o[e] = f2bf(fc2w[(size_t)(kbase+e)*256 + n]);
    *(bf16x8*)(w2p + (size_t)id*8) = o;
  } else {
    // 4096 fragment-chunks: idx = ((h*2+mt)*4+kt)*64 + lane
    #pragma unroll
    for (int k = 0; k < 16; ++k) {
      int idx = t + k*256;
      int lane = idx & 63;
      int kt = (idx >> 6) & 3;
      int mt = (idx >> 8) & 1;
      int h  = idx >> 9;
      int i  = mt*32 + (lane & 31);
      int jb = kt*16 + (lane >> 5)*8;
      bf16x8 o;
      #pragma unroll
      for (int e = 0; e < 8; ++e) {
        int j = jb + e;
        float v = (i < 49 && j < 49) ? spw[(size_t)(h*49 + i)*49 + j] : 0.f;
        o[e] = f2bf(v);
      }
      *(bf16x8*)(wspA + (size_t)idx*8) = o;
    }
  }
}

// ---------------- K1: LN1 + spatial window MLP (MFMA) + residual -> x1 (=d_out) ----------------
// 1296 blocks x 512 thr; 2 windows/block; wave = head. LDS: lxT 64 KB + murs ~0.9 KB -> 2 blk/CU.
// Pass1 batches all row-loads before reducing.
__global__ __launch_bounds__(512,4) void win_k(
    const float* __restrict__ x, const float* __restrict__ n1w, const float* __restrict__ n1b,
    const float* __restrict__ spb, const short* __restrict__ wspA,
    float* __restrict__ x1)
{
  extern __shared__ char wsm[];
  char*  lxT  = wsm;                      // 65536
  float* murs = (float*)(wsm + 65536);    // [2][56][2]
  int t = threadIdx.x, lane = t & 63, wave = t >> 6;
  int bid = blockIdx.x;

  // ---- LN stats: batched loads (one latency exposure), then independent reduces ----
  {
    f32x4 xv[2][7];
    #pragma unroll
    for (int w = 0; w < 2; ++w) {
      int win = bid*2 + w;
      int b = win/81, rem = win - b*81, wi = rem/9, wj = rem - (rem/9)*9;
      #pragma unroll
      for (int j = 0; j < 7; ++j) {
        int i = wave + 8*j;
        int iy = i/7, ix = i - iy*7;
        int hh = wi*7 + iy - 4, ww = wj*7 + ix - 4;
        bool valid = (i < 49) && hh >= 0 && hh < 56 && ww >= 0 && ww < 56;  // wave-uniform
        if (valid)
          xv[w][j] = *(const f32x4*)(x + ((size_t)(b*IMG + hh*56 + ww))*256 + lane*4);
      }
    }
    #pragma unroll
    for (int w = 0; w < 2; ++w) {
      int win = bid*2 + w;
      int b = win/81, rem = win - b*81, wi = rem/9, wj = rem - (rem/9)*9;
      #pragma unroll
      for (int j = 0; j < 7; ++j) {
        int i = wave + 8*j;
        int iy = i/7, ix = i - iy*7;
        int hh = wi*7 + iy - 4, ww = wj*7 + ix - 4;
        bool valid = (i < 49) && hh >= 0 && hh < 56 && ww >= 0 && ww < 56;  // wave-uniform
        if (!valid) continue;
        f32x4 v = xv[w][j];
        float s  = v[0]+v[1]+v[2]+v[3];
        float s2 = v[0]*v[0]+v[1]*v[1]+v[2]*v[2]+v[3]*v[3];
        #pragma unroll
        for (int m = 1; m < 64; m <<= 1) { s += __shfl_xor(s, m); s2 += __shfl_xor(s2, m); }
        float mu = s * (1.f/256.f);
        float rs = rsqrtf(s2*(1.f/256.f) - mu*mu + 1e-5f);
        if (lane == 0) { murs[(w*56+i)*2] = mu; murs[(w*56+i)*2+1] = rs; }
      }
    }
  }
  __syncthreads();

  // ---- pass2: thread = (win, c); column-read x, LN-apply, write x^T bf16 into lxT ----
  {
    int w = t >> 8, c = t & 255;
    int win = bid*2 + w;
    int b = win/81, rem = win - b*81, wi = rem/9, wj = rem - (rem/9)*9;
    float nwc = n1w[c], nbc = n1b[c];
    char* rowb = lxT + c*256;
    #pragma unroll
    for (int cj = 0; cj < 7; ++cj) {
      float vals[8];
      #pragma unroll
      for (int e = 0; e < 8; ++e) {
        int p = cj*8 + e;                 // compile-time
        float fv = 0.f;
        if (p < 49) {
          int iy = p/7, ix = p - iy*7;    // compile-time
          int hh = wi*7 + iy - 4, ww = wj*7 + ix - 4;
          if (hh >= 0 && hh < 56 && ww >= 0 && ww < 56) {   // wave-uniform
            float mu = murs[(w*56+p)*2], rs = murs[(w*56+p)*2+1];
            float xv = x[((size_t)(b*IMG + hh*56 + ww))*256 + c];
            fv = (xv - mu)*rs*nwc + nbc;
          }
        }
        vals[e] = fv;
      }
      i32x4 pk;
      pk[0] = cvtpk(vals[0], vals[1]); pk[1] = cvtpk(vals[2], vals[3]);
      pk[2] = cvtpk(vals[4], vals[5]); pk[3] = cvtpk(vals[6], vals[7]);
      *(i32x4*)(rowb + SWZA(w*128 + cj*16, c)) = pk;
    }
    i32x4 z = {0,0,0,0};
    *(i32x4*)(rowb + SWZA(w*128 + 112, c)) = z;   // j 56..63 pad
  }
  __syncthreads();

  // ---- MFMA dot: wave = head; 2 windows; i-tiles mt=0,1; K=49(pad 64) over 4 kt ----
  int h = wave, d = lane & 31, lk = lane >> 5;
  const short* wA = wspA + h*4096;
  int c = h*32 + d;
  f32x16 a00, a01, a10, a11;   // [mt][win]
  #pragma unroll
  for (int q = 0; q < 16; ++q) { a00[q]=0.f; a01[q]=0.f; a10[q]=0.f; a11[q]=0.f; }
  #pragma unroll
  for (int kt = 0; kt < 4; ++kt) {
    bf16x8 A0 = *(const bf16x8*)(wA + (kt*64 + lane)*8);
    bf16x8 A1 = *(const bf16x8*)(wA + ((4+kt)*64 + lane)*8);
    int bo = kt*32 + lk*16;
    bf16x8 B0 = *(const bf16x8*)(lxT + c*256 + SWZA(bo, c));
    bf16x8 B1 = *(const bf16x8*)(lxT + c*256 + SWZA(128 + bo, c));
    a00 = __builtin_amdgcn_mfma_f32_32x32x16_bf16(A0, B0, a00, 0,0,0);
    a10 = __builtin_amdgcn_mfma_f32_32x32x16_bf16(A1, B0, a10, 0,0,0);
    a01 = __builtin_amdgcn_mfma_f32_32x32x16_bf16(A0, B1, a01, 0,0,0);
    a11 = __builtin_amdgcn_mfma_f32_32x32x16_bf16(A1, B1, a11, 0,0,0);
  }

  // ---- epilogue: x1 = x + spatial + bias ----
  #pragma unroll
  for (int w = 0; w < 2; ++w) {
    int win = bid*2 + w;
    int b = win/81, rem = win - b*81, wi = rem/9, wj = rem - (rem/9)*9;
    #pragma unroll
    for (int mt = 0; mt < 2; ++mt) {
      #pragma unroll
      for (int r = 0; r < 16; ++r) {
        int i = mt*32 + (r&3) + 8*(r>>2) + 4*lk;
        if (i < 49) {
          int iy = i/7, ix = i - iy*7;
          int hh = wi*7 + iy - 4, ww = wj*7 + ix - 4;
          if (hh >= 0 && hh < 56 && ww >= 0 && ww < 56) {
            size_t off = ((size_t)(b*IMG + hh*56 + ww))*256 + c;
            float av = mt==0 ? (w==0 ? a00[r] : a01[r]) : (w==0 ? a10[r] : a11[r]);
            x1[off] = x[off] + av + spb[h*49 + i];
          }
        }
      }
    }
  }
}

// ---------------- K2: fused LN2 + fc1 + GeLU + fc2 + residual (in-place on d_out) ----------------
// 1568 blocks x 512 thr (8 waves). 64-row tile. LDS: a2[64][512B] + hc[64][512B] = 64 KB
// -> 2 blocks/CU. Champion structure (R13/R14): per-phase local pointers, phase-local
// depth-4 bq queue, setprio around MFMA, paired cvt_pk GeLU, last trailing barrier elided.
__global__ __launch_bounds__(512,4) void mlp_k(
    const float* __restrict__ x1, float* __restrict__ out,
    const short* __restrict__ w1p, const short* __restrict__ w2p,
    const float* __restrict__ n2w, const float* __restrict__ n2b,
    const float* __restrict__ b1, const float* __restrict__ b2)
{
  extern __shared__ char sm[];
  char* a2  = sm;                 // 32768
  char* hcb = sm + 32768;         // 32768

  int t = threadIdx.x, lane = t & 63, wave = t >> 6;
  int m0 = blockIdx.x * 64;

  // ---- Phase A: LN2 of 64 rows -> a2 (bf16, swizzled) ----
  {
    f32x4 nw = *(const f32x4*)(n2w + lane*4);
    f32x4 nb = *(const f32x4*)(n2b + lane*4);
    #pragma unroll
    for (int rq = 0; rq < 8; ++rq) {
      int rr = wave*8 + rq;
      f32x4 v = *(const f32x4*)(x1 + (size_t)(m0+rr)*256 + lane*4);
      float s  = v[0]+v[1]+v[2]+v[3];
      float s2 = v[0]*v[0]+v[1]*v[1]+v[2]*v[2]+v[3]*v[3];
      #pragma unroll
      for (int m = 1; m < 64; m <<= 1){ s += __shfl_xor(s,m); s2 += __shfl_xor(s2,m); }
      float mu = s*(1.f/256.f);
      float rs = rsqrtf(s2*(1.f/256.f) - mu*mu + 1e-5f);
      float y0 = (v[0]-mu)*rs*nw[0] + nb[0];
      float y1 = (v[1]-mu)*rs*nw[1] + nb[1];
      float y2 = (v[2]-mu)*rs*nw[2] + nb[2];
      float y3 = (v[3]-mu)*rs*nw[3] + nb[3];
      i32x2 pk; pk[0] = cvtpk(y0,y1); pk[1] = cvtpk(y2,y3);
      *(i32x2*)(a2 + SWZA(lane*8, rr) + rr*512) = pk;
    }
  }
  __syncthreads();

  int lr = lane & 31, lk = lane >> 5;
  int wn = wave;                      // 8 col-slices of 32

  f32x16 accO[2];
  #pragma unroll
  for (int i=0;i<2;++i)
    #pragma unroll
    for (int q=0;q<16;++q) accO[i][q] = 0.f;

  for (int ch = 0; ch < 4; ++ch) {
    f32x16 accH[2];
    #pragma unroll
    for (int i=0;i<2;++i)
      #pragma unroll
      for (int q=0;q<16;++q) accH[i][q] = 0.f;

    // ---- GEMM1: accH[64m][32n] = a2[64][256] @ W1-chunk ----
    const short* w1f = w1p + ((size_t)((ch*8 + wn)*16)*64 + lane)*8;
    bf16x8 bq[4];
    #pragma unroll
    for (int k = 0; k < 4; ++k) bq[k] = *(const bf16x8*)(w1f + (size_t)k*512);
    __builtin_amdgcn_s_setprio(1);
    #pragma unroll
    for (int kk = 0; kk < 16; ++kk) {
      bf16x8 b = bq[kk & 3];
      if (kk < 12) bq[kk & 3] = *(const bf16x8*)(w1f + (size_t)(kk+4)*512);
      int kb = kk*32 + lk*16;
      bf16x8 a0 = *(const bf16x8*)(a2 + SWZA(kb, lr) + lr*512);
      bf16x8 a1 = *(const bf16x8*)(a2 + SWZA(kb, 32+lr) + (32+lr)*512);
      accH[0] = __builtin_amdgcn_mfma_f32_32x32x16_bf16(a0, b, accH[0], 0,0,0);
      accH[1] = __builtin_amdgcn_mfma_f32_32x32x16_bf16(a1, b, accH[1], 0,0,0);
    }
    __builtin_amdgcn_s_setprio(0);

    // ---- bias + GeLU -> hc (bf16, swizzled); paired cvt_pk ----
    {
      float b1v = b1[ch*256 + wn*32 + lr];
      int colb = (wn*32 + lr)*2;
      #pragma unroll
      for (int ms = 0; ms < 2; ++ms) {
        #pragma unroll
        for (int r2 = 0; r2 < 8; ++r2) {
          int r = r2*2;
          float g0 = gelu_s(accH[ms][r]   + b1v);
          float g1 = gelu_s(accH[ms][r+1] + b1v);
          unsigned pw = cvtpk(g0, g1);
          int row0 = ms*32 + (r&3) + 8*(r>>2) + 4*lk;   // r even
          int row1 = row0 + 1;
          *(short*)(hcb + SWZA(colb, row0) + row0*512) = (short)(pw & 0xffffu);
          *(short*)(hcb + SWZA(colb, row1) + row1*512) = (short)(pw >> 16);
        }
      }
    }
    __syncthreads();

    // ---- GEMM2: accO[64m][32n] += hc[64][256] @ W2-chunk ----
    const short* w2f = w2p + ((size_t)(wn*64 + ch*16)*64 + lane)*8;
    #pragma unroll
    for (int k = 0; k < 4; ++k) bq[k] = *(const bf16x8*)(w2f + (size_t)k*512);
    __builtin_amdgcn_s_setprio(1);
    #pragma unroll
    for (int kk = 0; kk < 16; ++kk) {
      bf16x8 b = bq[kk & 3];
      if (kk < 12) bq[kk & 3] = *(const bf16x8*)(w2f + (size_t)(kk+4)*512);
      int kb = kk*32 + lk*16;
      bf16x8 a0 = *(const bf16x8*)(hcb + SWZA(kb, lr) + lr*512);
      bf16x8 a1 = *(const bf16x8*)(hcb + SWZA(kb, 32+lr) + (32+lr)*512);
      accO[0] = __builtin_amdgcn_mfma_f32_32x32x16_bf16(a0, b, accO[0], 0,0,0);
      accO[1] = __builtin_amdgcn_mfma_f32_32x32x16_bf16(a1, b, accO[1], 0,0,0);
    }
    __builtin_amdgcn_s_setprio(0);
    if (ch < 3) __syncthreads();   // protect hc before next chunk's GeLU (dead on last chunk)
  }

  // ---- epilogue: out = x1 + accO + b2 ----
  {
    int col = wn*32 + lr;
    float b2v = b2[col];
    #pragma unroll
    for (int ms = 0; ms < 2; ++ms) {
      #pragma unroll
      for (int r = 0; r < 16; ++r) {
        int row = ms*32 + (r&3) + 8*(r>>2) + 4*lk;
        size_t off = (size_t)(m0 + row)*256 + col;
        out[off] = x1[off] + accO[ms][r] + b2v;
      }
    }
  }
}

extern "C" void kernel_launch(void* const* d_in, const int* in_sizes, int n_in,
                              void* d_out, int out_size, void* d_ws, size_t ws_size,
                              hipStream_t stream) {
  const float* x    = (const float*)d_in[0];
  const float* n1w  = (const float*)d_in[1];
  const float* n1b  = (const float*)d_in[2];
  const float* spw  = (const float*)d_in[3];
  const float* spb  = (const float*)d_in[4];
  const float* n2w  = (const float*)d_in[5];
  const float* n2b  = (const float*)d_in[6];
  const float* fc1w = (const float*)d_in[7];
  const float* fc1b = (const float*)d_in[8];
  const float* fc2w = (const float*)d_in[9];
  const float* fc2b = (const float*)d_in[10];
  float* outp = (float*)d_out;

  char* ws = (char*)d_ws;
  short* w1p  = (short*)ws;                   // 524288 B
  short* w2p  = (short*)(ws + 524288);        // 524288 B
  short* wspA = (short*)(ws + 1048576);       // 65536 B

  prep_k<<<257, 256, 0, stream>>>(fc1w, fc2w, spw, w1p, w2p, wspA);

  hipFuncSetAttribute(reinterpret_cast<const void*>(win_k),
                      hipFuncAttributeMaxDynamicSharedMemorySize, 66432);
  win_k<<<1296, 512, 66432, stream>>>(x, n1w, n1b, spb, wspA, outp);

  hipFuncSetAttribute(reinterpret_cast<const void*>(mlp_k),
                      hipFuncAttributeMaxDynamicSharedMemorySize, 65536);
  mlp_k<<<MTOT/64, 512, 65536, stream>>>(outp, outp, w1p, w2p, n2w, n2b, fc1b, fc2b);
}

// Round 17
// 287.597 us; speedup vs baseline: 1.0595x; 1.0062x over previous
//
#include <hip/hip_runtime.h>
#include <hip/hip_bf16.h>

#define NHEAD 8
#define IMG   3136      // 56*56
#define MTOT  100352    // 32*3136
#define NWIN  1296      // win-path blocks in fused win_k

typedef __attribute__((ext_vector_type(2))) _Float16 f16x2;
typedef __attribute__((ext_vector_type(4))) float    f32x4;
typedef __attribute__((ext_vector_type(16))) float   f32x16;
typedef __attribute__((ext_vector_type(8))) short    bf16x8;
typedef __attribute__((ext_vector_type(2))) int      i32x2;
typedef __attribute__((ext_vector_type(4))) int      i32x4;

// swizzle for 512B rows: row bits 0-2 -> byte bits 4-6, row bit 3 -> byte bit 7 (bijective)
#define SWZA(byteoff, r) ((byteoff) ^ (((r)&7)<<4) ^ ((((r)>>3)&1)<<7))

__device__ __forceinline__ short f2bf(float f){
  union { float fv; unsigned u; } a; a.fv = f;
  unsigned u = a.u;
  unsigned r = (u + 0x7fffu + ((u >> 16) & 1u)) >> 16;
  return (short)r;
}

// hardware packed f32->bf16 (RNE), 1 instruction for 2 values
__device__ __forceinline__ unsigned cvtpk(float lo, float hi){
  unsigned r;
  asm("v_cvt_pk_bf16_f32 %0, %1, %2" : "=v"(r) : "v"(lo), "v"(hi));
  return r;
}

// sigmoid-form GeLU: v*sigmoid(1.702v). Verified within threshold (R9-R16 absmax 0.03125).
__device__ __forceinline__ float gelu_s(float v){
  float e = __expf(-1.702f*v);
  return v*__builtin_amdgcn_rcpf(1.f + e);
}

// ---------------- K0: spatial weight prep only (1 block) ----------------
// spatial W -> MFMA A-frag pack wspA[h][mt][kt][lane][8] bf16 (i,j zero-padded)
__global__ void prep_k(const float* __restrict__ spw, short* __restrict__ wspA)
{
  int t = threadIdx.x;
  // 4096 fragment-chunks: idx = ((h*2+mt)*4+kt)*64 + lane
  #pragma unroll
  for (int k = 0; k < 16; ++k) {
    int idx = t + k*256;
    int lane = idx & 63;
    int kt = (idx >> 6) & 3;
    int mt = (idx >> 8) & 1;
    int h  = idx >> 9;
    int i  = mt*32 + (lane & 31);
    int jb = kt*16 + (lane >> 5)*8;
    bf16x8 o;
    #pragma unroll
    for (int e = 0; e < 8; ++e) {
      int j = jb + e;
      float v = (i < 49 && j < 49) ? spw[(size_t)(h*49 + i)*49 + j] : 0.f;
      o[e] = f2bf(v);
    }
    *(bf16x8*)(wspA + (size_t)idx*8) = o;
  }
}

// ---------------- K1: LN1 + spatial window MLP (MFMA) + residual -> x1 (=d_out) ----------------
// Blocks 0..1295: win path (2 windows/block; wave = head; LDS lxT 64 KB -> 2 blk/CU).
// Blocks 1296..1423: fc-weight fragment packing (hidden under win work; only mlp_k reads it).
__global__ __launch_bounds__(512,4) void win_k(
    const float* __restrict__ x, const float* __restrict__ n1w, const float* __restrict__ n1b,
    const float* __restrict__ spb, const short* __restrict__ wspA,
    float* __restrict__ x1,
    const float* __restrict__ fc1w, const float* __restrict__ fc2w,
    short* __restrict__ w1p, short* __restrict__ w2p)
{
  int bid = blockIdx.x;
  int t = threadIdx.x;

  if (bid >= NWIN) {
    // ---- fc weight packing path (no barriers, no LDS) ----
    int fb = bid - NWIN;
    if (fb < 64) {
      int id = fb*512 + t;             // [0, 32768)
      int l = id & 63, fk = id >> 6;   // fk = f*16+kk
      int kk = fk & 15, f = fk >> 4;
      int n = f*32 + (l & 31);
      int kbase = kk*16 + (l >> 5)*8;
      bf16x8 o;
      #pragma unroll
      for (int e = 0; e < 8; ++e) o[e] = f2bf(fc1w[(size_t)(kbase+e)*1024 + n]);
      *(bf16x8*)(w1p + (size_t)id*8) = o;
    } else {
      int id = (fb-64)*512 + t;        // [0, 32768)
      int l = id & 63, fk = id >> 6;   // fk = f*64+kk
      int kk = fk & 63, f = fk >> 6;
      int n = f*32 + (l & 31);
      int kbase = kk*16 + (l >> 5)*8;
      bf16x8 o;
      #pragma unroll
      for (int e = 0; e < 8; ++e) o[e] = f2bf(fc2w[(size_t)(kbase+e)*256 + n]);
      *(bf16x8*)(w2p + (size_t)id*8) = o;
    }
    return;
  }

  extern __shared__ char wsm[];
  char*  lxT  = wsm;                      // 65536
  float* murs = (float*)(wsm + 65536);    // [2][56][2]
  int lane = t & 63, wave = t >> 6;

  // ---- LN stats: batched loads (one latency exposure), then independent reduces ----
  {
    f32x4 xv[2][7];
    #pragma unroll
    for (int w = 0; w < 2; ++w) {
      int win = bid*2 + w;
      int b = win/81, rem = win - b*81, wi = rem/9, wj = rem - (rem/9)*9;
      #pragma unroll
      for (int j = 0; j < 7; ++j) {
        int i = wave + 8*j;
        int iy = i/7, ix = i - iy*7;
        int hh = wi*7 + iy - 4, ww = wj*7 + ix - 4;
        bool valid = (i < 49) && hh >= 0 && hh < 56 && ww >= 0 && ww < 56;  // wave-uniform
        if (valid)
          xv[w][j] = *(const f32x4*)(x + ((size_t)(b*IMG + hh*56 + ww))*256 + lane*4);
      }
    }
    #pragma unroll
    for (int w = 0; w < 2; ++w) {
      int win = bid*2 + w;
      int b = win/81, rem = win - b*81, wi = rem/9, wj = rem - (rem/9)*9;
      #pragma unroll
      for (int j = 0; j < 7; ++j) {
        int i = wave + 8*j;
        int iy = i/7, ix = i - iy*7;
        int hh = wi*7 + iy - 4, ww = wj*7 + ix - 4;
        bool valid = (i < 49) && hh >= 0 && hh < 56 && ww >= 0 && ww < 56;  // wave-uniform
        if (!valid) continue;
        f32x4 v = xv[w][j];
        float s  = v[0]+v[1]+v[2]+v[3];
        float s2 = v[0]*v[0]+v[1]*v[1]+v[2]*v[2]+v[3]*v[3];
        #pragma unroll
        for (int m = 1; m < 64; m <<= 1) { s += __shfl_xor(s, m); s2 += __shfl_xor(s2, m); }
        float mu = s * (1.f/256.f);
        float rs = rsqrtf(s2*(1.f/256.f) - mu*mu + 1e-5f);
        if (lane == 0) { murs[(w*56+i)*2] = mu; murs[(w*56+i)*2+1] = rs; }
      }
    }
  }
  __syncthreads();

  // ---- pass2: thread = (win, c); column-read x, LN-apply, write x^T bf16 into lxT ----
  {
    int w = t >> 8, c = t & 255;
    int win = bid*2 + w;
    int b = win/81, rem = win - b*81, wi = rem/9, wj = rem - (rem/9)*9;
    float nwc = n1w[c], nbc = n1b[c];
    char* rowb = lxT + c*256;
    #pragma unroll
    for (int cj = 0; cj < 7; ++cj) {
      float vals[8];
      #pragma unroll
      for (int e = 0; e < 8; ++e) {
        int p = cj*8 + e;                 // compile-time
        float fv = 0.f;
        if (p < 49) {
          int iy = p/7, ix = p - iy*7;    // compile-time
          int hh = wi*7 + iy - 4, ww = wj*7 + ix - 4;
          if (hh >= 0 && hh < 56 && ww >= 0 && ww < 56) {   // wave-uniform
            float mu = murs[(w*56+p)*2], rs = murs[(w*56+p)*2+1];
            float xv = x[((size_t)(b*IMG + hh*56 + ww))*256 + c];
            fv = (xv - mu)*rs*nwc + nbc;
          }
        }
        vals[e] = fv;
      }
      i32x4 pk;
      pk[0] = cvtpk(vals[0], vals[1]); pk[1] = cvtpk(vals[2], vals[3]);
      pk[2] = cvtpk(vals[4], vals[5]); pk[3] = cvtpk(vals[6], vals[7]);
      *(i32x4*)(rowb + SWZA(w*128 + cj*16, c)) = pk;
    }
    i32x4 z = {0,0,0,0};
    *(i32x4*)(rowb + SWZA(w*128 + 112, c)) = z;   // j 56..63 pad
  }
  __syncthreads();

  // ---- MFMA dot: wave = head; 2 windows; i-tiles mt=0,1; K=49(pad 64) over 4 kt ----
  int h = wave, d = lane & 31, lk = lane >> 5;
  const short* wA = wspA + h*4096;
  int c = h*32 + d;
  f32x16 a00, a01, a10, a11;   // [mt][win]
  #pragma unroll
  for (int q = 0; q < 16; ++q) { a00[q]=0.f; a01[q]=0.f; a10[q]=0.f; a11[q]=0.f; }
  #pragma unroll
  for (int kt = 0; kt < 4; ++kt) {
    bf16x8 A0 = *(const bf16x8*)(wA + (kt*64 + lane)*8);
    bf16x8 A1 = *(const bf16x8*)(wA + ((4+kt)*64 + lane)*8);
    int bo = kt*32 + lk*16;
    bf16x8 B0 = *(const bf16x8*)(lxT + c*256 + SWZA(bo, c));
    bf16x8 B1 = *(const bf16x8*)(lxT + c*256 + SWZA(128 + bo, c));
    a00 = __builtin_amdgcn_mfma_f32_32x32x16_bf16(A0, B0, a00, 0,0,0);
    a10 = __builtin_amdgcn_mfma_f32_32x32x16_bf16(A1, B0, a10, 0,0,0);
    a01 = __builtin_amdgcn_mfma_f32_32x32x16_bf16(A0, B1, a01, 0,0,0);
    a11 = __builtin_amdgcn_mfma_f32_32x32x16_bf16(A1, B1, a11, 0,0,0);
  }

  // ---- epilogue: x1 = x + spatial + bias ----
  #pragma unroll
  for (int w = 0; w < 2; ++w) {
    int win = bid*2 + w;
    int b = win/81, rem = win - b*81, wi = rem/9, wj = rem - (rem/9)*9;
    #pragma unroll
    for (int mt = 0; mt < 2; ++mt) {
      #pragma unroll
      for (int r = 0; r < 16; ++r) {
        int i = mt*32 + (r&3) + 8*(r>>2) + 4*lk;
        if (i < 49) {
          int iy = i/7, ix = i - iy*7;
          int hh = wi*7 + iy - 4, ww = wj*7 + ix - 4;
          if (hh >= 0 && hh < 56 && ww >= 0 && ww < 56) {
            size_t off = ((size_t)(b*IMG + hh*56 + ww))*256 + c;
            float av = mt==0 ? (w==0 ? a00[r] : a01[r]) : (w==0 ? a10[r] : a11[r]);
            x1[off] = x[off] + av + spb[h*49 + i];
          }
        }
      }
    }
  }
}

// ---------------- K2: fused LN2 + fc1 + GeLU + fc2 + residual (in-place on d_out) ----------------
// 1568 blocks x 512 thr (8 waves). 64-row tile. LDS: a2[64][512B] + hc[64][512B] = 64 KB
// -> 2 blocks/CU. Champion structure (R13/R14): per-phase local pointers, phase-local
// depth-4 bq queue, setprio around MFMA, paired cvt_pk GeLU, last trailing barrier elided.
__global__ __launch_bounds__(512,4) void mlp_k(
    const float* __restrict__ x1, float* __restrict__ out,
    const short* __restrict__ w1p, const short* __restrict__ w2p,
    const float* __restrict__ n2w, const float* __restrict__ n2b,
    const float* __restrict__ b1, const float* __restrict__ b2)
{
  extern __shared__ char sm[];
  char* a2  = sm;                 // 32768
  char* hcb = sm + 32768;         // 32768

  int t = threadIdx.x, lane = t & 63, wave = t >> 6;
  int m0 = blockIdx.x * 64;

  // ---- Phase A: LN2 of 64 rows -> a2 (bf16, swizzled) ----
  {
    f32x4 nw = *(const f32x4*)(n2w + lane*4);
    f32x4 nb = *(const f32x4*)(n2b + lane*4);
    #pragma unroll
    for (int rq = 0; rq < 8; ++rq) {
      int rr = wave*8 + rq;
      f32x4 v = *(const f32x4*)(x1 + (size_t)(m0+rr)*256 + lane*4);
      float s  = v[0]+v[1]+v[2]+v[3];
      float s2 = v[0]*v[0]+v[1]*v[1]+v[2]*v[2]+v[3]*v[3];
      #pragma unroll
      for (int m = 1; m < 64; m <<= 1){ s += __shfl_xor(s,m); s2 += __shfl_xor(s2,m); }
      float mu = s*(1.f/256.f);
      float rs = rsqrtf(s2*(1.f/256.f) - mu*mu + 1e-5f);
      float y0 = (v[0]-mu)*rs*nw[0] + nb[0];
      float y1 = (v[1]-mu)*rs*nw[1] + nb[1];
      float y2 = (v[2]-mu)*rs*nw[2] + nb[2];
      float y3 = (v[3]-mu)*rs*nw[3] + nb[3];
      i32x2 pk; pk[0] = cvtpk(y0,y1); pk[1] = cvtpk(y2,y3);
      *(i32x2*)(a2 + SWZA(lane*8, rr) + rr*512) = pk;
    }
  }
  __syncthreads();

  int lr = lane & 31, lk = lane >> 5;
  int wn = wave;                      // 8 col-slices of 32

  f32x16 accO[2];
  #pragma unroll
  for (int i=0;i<2;++i)
    #pragma unroll
    for (int q=0;q<16;++q) accO[i][q] = 0.f;

  for (int ch = 0; ch < 4; ++ch) {
    f32x16 accH[2];
    #pragma unroll
    for (int i=0;i<2;++i)
      #pragma unroll
      for (int q=0;q<16;++q) accH[i][q] = 0.f;

    // ---- GEMM1: accH[64m][32n] = a2[64][256] @ W1-chunk ----
    const short* w1f = w1p + ((size_t)((ch*8 + wn)*16)*64 + lane)*8;
    bf16x8 bq[4];
    #pragma unroll
    for (int k = 0; k < 4; ++k) bq[k] = *(const bf16x8*)(w1f + (size_t)k*512);
    __builtin_amdgcn_s_setprio(1);
    #pragma unroll
    for (int kk = 0; kk < 16; ++kk) {
      bf16x8 b = bq[kk & 3];
      if (kk < 12) bq[kk & 3] = *(const bf16x8*)(w1f + (size_t)(kk+4)*512);
      int kb = kk*32 + lk*16;
      bf16x8 a0 = *(const bf16x8*)(a2 + SWZA(kb, lr) + lr*512);
      bf16x8 a1 = *(const bf16x8*)(a2 + SWZA(kb, 32+lr) + (32+lr)*512);
      accH[0] = __builtin_amdgcn_mfma_f32_32x32x16_bf16(a0, b, accH[0], 0,0,0);
      accH[1] = __builtin_amdgcn_mfma_f32_32x32x16_bf16(a1, b, accH[1], 0,0,0);
    }
    __builtin_amdgcn_s_setprio(0);

    // ---- bias + GeLU -> hc (bf16, swizzled); paired cvt_pk ----
    {
      float b1v = b1[ch*256 + wn*32 + lr];
      int colb = (wn*32 + lr)*2;
      #pragma unroll
      for (int ms = 0; ms < 2; ++ms) {
        #pragma unroll
        for (int r2 = 0; r2 < 8; ++r2) {
          int r = r2*2;
          float g0 = gelu_s(accH[ms][r]   + b1v);
          float g1 = gelu_s(accH[ms][r+1] + b1v);
          unsigned pw = cvtpk(g0, g1);
          int row0 = ms*32 + (r&3) + 8*(r>>2) + 4*lk;   // r even
          int row1 = row0 + 1;
          *(short*)(hcb + SWZA(colb, row0) + row0*512) = (short)(pw & 0xffffu);
          *(short*)(hcb + SWZA(colb, row1) + row1*512) = (short)(pw >> 16);
        }
      }
    }
    __syncthreads();

    // ---- GEMM2: accO[64m][32n] += hc[64][256] @ W2-chunk ----
    const short* w2f = w2p + ((size_t)(wn*64 + ch*16)*64 + lane)*8;
    #pragma unroll
    for (int k = 0; k < 4; ++k) bq[k] = *(const bf16x8*)(w2f + (size_t)k*512);
    __builtin_amdgcn_s_setprio(1);
    #pragma unroll
    for (int kk = 0; kk < 16; ++kk) {
      bf16x8 b = bq[kk & 3];
      if (kk < 12) bq[kk & 3] = *(const bf16x8*)(w2f + (size_t)(kk+4)*512);
      int kb = kk*32 + lk*16;
      bf16x8 a0 = *(const bf16x8*)(hcb + SWZA(kb, lr) + lr*512);
      bf16x8 a1 = *(const bf16x8*)(hcb + SWZA(kb, 32+lr) + (32+lr)*512);
      accO[0] = __builtin_amdgcn_mfma_f32_32x32x16_bf16(a0, b, accO[0], 0,0,0);
      accO[1] = __builtin_amdgcn_mfma_f32_32x32x16_bf16(a1, b, accO[1], 0,0,0);
    }
    __builtin_amdgcn_s_setprio(0);
    if (ch < 3) __syncthreads();   // protect hc before next chunk's GeLU (dead on last chunk)
  }

  // ---- epilogue: out = x1 + accO + b2 ----
  {
    int col = wn*32 + lr;
    float b2v = b2[col];
    #pragma unroll
    for (int ms = 0; ms < 2; ++ms) {
      #pragma unroll
      for (int r = 0; r < 16; ++r) {
        int row = ms*32 + (r&3) + 8*(r>>2) + 4*lk;
        size_t off = (size_t)(m0 + row)*256 + col;
        out[off] = x1[off] + accO[ms][r] + b2v;
      }
    }
  }
}

extern "C" void kernel_launch(void* const* d_in, const int* in_sizes, int n_in,
                              void* d_out, int out_size, void* d_ws, size_t ws_size,
                              hipStream_t stream) {
  const float* x    = (const float*)d_in[0];
  const float* n1w  = (const float*)d_in[1];
  const float* n1b  = (const float*)d_in[2];
  const float* spw  = (const float*)d_in[3];
  const float* spb  = (const float*)d_in[4];
  const float* n2w  = (const float*)d_in[5];
  const float* n2b  = (const float*)d_in[6];
  const float* fc1w = (const float*)d_in[7];
  const float* fc1b = (const float*)d_in[8];
  const float* fc2w = (const float*)d_in[9];
  const float* fc2b = (const float*)d_in[10];
  float* outp = (float*)d_out;

  char* ws = (char*)d_ws;
  short* w1p  = (short*)ws;                   // 524288 B
  short* w2p  = (short*)(ws + 524288);        // 524288 B
  short* wspA = (short*)(ws + 1048576);       // 65536 B

  prep_k<<<1, 256, 0, stream>>>(spw, wspA);

  hipFuncSetAttribute(reinterpret_cast<const void*>(win_k),
                      hipFuncAttributeMaxDynamicSharedMemorySize, 66432);
  win_k<<<NWIN + 128, 512, 66432, stream>>>(x, n1w, n1b, spb, wspA, outp,
                                            fc1w, fc2w, w1p, w2p);

  hipFuncSetAttribute(reinterpret_cast<const void*>(mlp_k),
                      hipFuncAttributeMaxDynamicSharedMemorySize, 65536);
  mlp_k<<<MTOT/64, 512, 65536, stream>>>(outp, outp, w1p, w2p, n2w, n2b, fc1b, fc2b);
}